// Round 12
// baseline (180.353 us; speedup 1.0000x reference)
//
#include <hip/hip_runtime.h>
#include <hip/hip_fp16.h>
#include <math.h>

#define HP   2080          // padded height (2048 + 2*16)
#define WP   2080          // padded width
#define MARG 16
#define WOUT 2048
#define HOUT 2048
#define RAD  16            // truncation radius; tail mass ~2e-7 (threshold 9.9e-3)
#define TSH  6
#define TDIM 33            // 33x33 canvas tiles of 64x64
#define NT   (TDIM * TDIM) // 1089 buckets
#define CAP  1536          // bucket capacity; expected max ~1170
#define OTD  32            // 32x32 output tiles of 64x64
#define PST  97            // patch row stride (96 cols + 1 pad -> stride mod 32 = 1, conflict-free)
#define NBLK 256
#define SCAT_T 1024
#define SCAT_IT 4          // 256*1024*4 >= N

// exact discrete tap via Poisson summation: g[n] = sqrt(pi/200)*exp(-pi^2 n^2/200)
__device__ __forceinline__ void make_weights(float* wreg) {
#pragma unroll
    for (int t = 0; t <= RAD; ++t)
        wreg[t] = 0.12533141373155003f * __expf(-0.04934802200544679f * (float)(t * t));
}

// 33-tap conv of a 40-window: acc[k] = sum_{j=k..k+32} W[j] * g[|j-k-16|]
__device__ __forceinline__ void conv8(const float* __restrict__ base, int stride,
                                      const float* __restrict__ wreg, float* __restrict__ a) {
#pragma unroll
    for (int k = 0; k < 8; ++k) a[k] = 0.0f;
#pragma unroll
    for (int j = 0; j < 40; ++j) {
        float v = base[j * stride];
#pragma unroll
        for (int k = 0; k < 8; ++k)
            if (j >= k && j <= k + 32)
                a[k] += v * wreg[(j - k - 16 < 0) ? (k + 16 - j) : (j - k - 16)];
    }
}

// ---------------------------------------------------------------------------
// pass 1: scatter into canvas-tile buckets (R10's proven version, 1.03x dup:
// points with cell row%64==63 / col%64==63 duplicated into the tile below /
// right, so each record's 2x2 footprint is tile-local, lr1/lc1 in [0,64]).
// ---------------------------------------------------------------------------
__global__ __launch_bounds__(SCAT_T) void scatter_kernel(const float2* __restrict__ pos,
                                                         const float* __restrict__ inten,
                                                         int* __restrict__ cursor,  // [NT], zeroed
                                                         ushort4* __restrict__ bins,
                                                         int n) {
    __shared__ int lhist[NT];
    __shared__ int lbase[NT];
    const int tid = threadIdx.x;
    for (int i = tid; i < NT; i += SCAT_T) lhist[i] = 0;
    __syncthreads();
    const int stride = NBLK * SCAT_T;
    const int start  = blockIdx.x * SCAT_T + tid;
    unsigned ra[SCAT_IT], rb[SCAT_IT], rc[SCAT_IT];
#pragma unroll
    for (int it = 0; it < SCAT_IT; ++it) {
        int i = start + it * stride;
        if (i < n) {
            float2 p = pos[i];
            float I  = inten[i];
            float px = p.x + MARG, py = p.y + MARG;
            int col = (int)floorf(px), row = (int)floorf(py);
            row = min(max(row, 0), HP - 1);
            col = min(max(col, 0), WP - 1);
            float dy = py - (float)row, dx = px - (float)col;
            ra[it] = ((unsigned)row << 12) | (unsigned)col;
            rb[it] = (unsigned)__half_as_ushort(__float2half(dx))
                   | ((unsigned)__half_as_ushort(__float2half(dy)) << 16);
            rc[it] = (unsigned)__half_as_ushort(__float2half(I));
            int tr = row >> 6, tc = col >> 6;
            int er = ((row & 63) == 63) ? 1 : 0;
            int ec = ((col & 63) == 63) ? 1 : 0;
            for (int dr = 0; dr <= er; ++dr)
                for (int dc = 0; dc <= ec; ++dc)
                    atomicAdd(&lhist[(tr + dr) * TDIM + tc + dc], 1);
        } else ra[it] = 0xffffffffu;
    }
    __syncthreads();
    for (int i = tid; i < NT; i += SCAT_T) {
        int c = lhist[i];
        lbase[i] = (c > 0) ? atomicAdd(&cursor[i], c) : 0;
        lhist[i] = 0;
    }
    __syncthreads();
#pragma unroll
    for (int it = 0; it < SCAT_IT; ++it) {
        if (ra[it] != 0xffffffffu) {
            int row = (int)(ra[it] >> 12), col = (int)(ra[it] & 4095u);
            int tr = row >> 6, tc = col >> 6;
            int er = ((row & 63) == 63) ? 1 : 0;
            int ec = ((col & 63) == 63) ? 1 : 0;
            for (int dr = 0; dr <= er; ++dr)
                for (int dc = 0; dc <= ec; ++dc) {
                    int b   = (tr + dr) * TDIM + tc + dc;
                    int lr1 = row - ((tr + dr) << 6) + 1;   // 0..64
                    int lc1 = col - ((tc + dc) << 6) + 1;   // 0..64
                    int off = atomicAdd(&lhist[b], 1);
                    int idx = lbase[b] + off;
                    if (idx < CAP) {
                        ushort4 rec;
                        rec.x = (unsigned short)((lr1 << 7) | lc1);
                        rec.y = (unsigned short)(rb[it] & 0xffffu);
                        rec.z = (unsigned short)(rb[it] >> 16);
                        rec.w = (unsigned short)rc[it];
                        bins[(size_t)b * CAP + idx] = rec;
                    }
                }
        }
    }
}

// ---------------------------------------------------------------------------
// pass 2 (fused): per 64x64 output tile. Gather records from the 4 buckets
// {ty,ty+1}x{tx,tx+1} (dedup: in a dr=1/dc=1 bucket, lr1=0/lc1=0 records are
// halo duplicates of the dr=0/dc=0 bucket -> skip; accept lr1,lc1 <= 32).
// Splat into a 96x96 LDS patch (canvas rows/cols 64*t .. 64*t+95), hconv with
// results written BACK into patch cols 0..63 (row r of hconv depends only on
// patch row r), then vconv + coalesced store. 37.2 KB LDS -> 4 blocks/CU.
// ---------------------------------------------------------------------------
__global__ __launch_bounds__(512, 8) void fused_kernel(const ushort4* __restrict__ bins,
                                                       const int* __restrict__ cursor,
                                                       float* __restrict__ out) {
    __shared__ float patch[96 * PST];   // 37.2 KB
    const int tid = threadIdx.x;
    const int tx  = blockIdx.x, ty = blockIdx.y;
    float wreg[RAD + 1];
    make_weights(wreg);

    for (int i = tid; i < 96 * PST; i += 512) patch[i] = 0.0f;
    __syncthreads();

    // --- splat from 4 buckets (patch row p = canvasrow - 64*ty) ---
    for (int q = 0; q < 4; ++q) {
        const int dr = q >> 1, dc = q & 1;
        const int bkt = (ty + dr) * TDIM + (tx + dc);
        const int cnt = min(cursor[bkt], CAP);
        const ushort4* bp = bins + (size_t)bkt * CAP;
        for (int i = tid; i < cnt; i += 512) {
            ushort4 r = bp[i];
            int lr1 = r.x >> 7, lc1 = r.x & 127;      // 0..64
            if ((dr && (lr1 < 1 || lr1 > 32)) || (dc && (lc1 < 1 || lc1 > 32))) continue;
            float dx = __half2float(__ushort_as_half(r.y));
            float dy = __half2float(__ushort_as_half(r.z));
            float I  = __half2float(__ushort_as_half(r.w));
            int p0 = (dr << 6) + lr1 - 1;             // cell row - 64*ty, in [-1,95]
            int c0 = (dc << 6) + lc1 - 1;             // in [-1,95]
            float wy0 = (1.0f - dy) * I, wy1 = dy * I;
            float wx0 = 1.0f - dx,      wx1 = dx;
            bool ca = (c0 >= 0), cb = (c0 <= 94);
            if (p0 >= 0) {
                if (ca) atomicAdd(&patch[p0 * PST + c0],     wy0 * wx0);
                if (cb) atomicAdd(&patch[p0 * PST + c0 + 1], wy0 * wx1);
            }
            if (p0 <= 94) {
                if (ca) atomicAdd(&patch[(p0 + 1) * PST + c0],     wy1 * wx0);
                if (cb) atomicAdd(&patch[(p0 + 1) * PST + c0 + 1], wy1 * wx1);
            }
        }
    }
    __syncthreads();

    // --- hconv: row r, col c (0..63): sum_s g[s]*patch[r][c+16+s] = conv8 of
    // patch[r][c0..c0+39]. All 768 row-tasks computed into registers first
    // (reads), then written back into patch cols 0..63 after the barrier.
    const int trA = tid >> 3;                 // 0..63
    const int cg  = (tid & 7) << 3;           // col group 0,8,...,56
    float aA[8], aB[8];
    conv8(&patch[trA * PST + cg], 1, wreg, aA);
    if (tid < 256) conv8(&patch[(64 + (tid >> 3)) * PST + cg], 1, wreg, aB);
    __syncthreads();
#pragma unroll
    for (int k = 0; k < 8; ++k) patch[trA * PST + cg + k] = aA[k];
    if (tid < 256) {
#pragma unroll
        for (int k = 0; k < 8; ++k) patch[(64 + (tid >> 3)) * PST + cg + k] = aB[k];
    }
    __syncthreads();

    // --- vconv + store: out[oy0+r][ox0+c] = sum_t g[t]*tmp[r+16+t][c] ---
    const int c  = tid & 63;
    const int r0 = (tid >> 6) << 3;           // 0,8,...,56
    float a[8];
    conv8(&patch[r0 * PST + c], PST, wreg, a);
    const int oy0 = ty << 6, ox0 = tx << 6;
#pragma unroll
    for (int k = 0; k < 8; ++k)
        out[(size_t)(oy0 + r0 + k) * WOUT + ox0 + c] = a[k];
}

extern "C" void kernel_launch(void* const* d_in, const int* in_sizes, int n_in,
                              void* d_out, int out_size, void* d_ws, size_t ws_size,
                              hipStream_t stream) {
    const float2* pos   = (const float2*)d_in[0];   // (N,2) as (x,y)
    const float*  inten = (const float*)d_in[1];
    int n = in_sizes[1];

    ushort4* bins   = (ushort4*)d_ws;                             // NT*CAP*8 = 13.4 MB
    int*     cursor = (int*)((char*)d_ws + (size_t)NT * CAP * 8); // NT ints

    hipMemsetAsync(cursor, 0, NT * sizeof(int), stream);          // 4.4 KB
    scatter_kernel<<<NBLK, SCAT_T, 0, stream>>>(pos, inten, cursor, bins, n);
    fused_kernel<<<dim3(OTD, OTD), 512, 0, stream>>>(bins, cursor, (float*)d_out);
}

// Round 13
// 165.282 us; speedup vs baseline: 1.0912x; 1.0912x over previous
//
#include <hip/hip_runtime.h>
#include <hip/hip_fp16.h>
#include <math.h>

#define HP   2080          // padded height (2048 + 2*16)
#define WP   2080          // padded width
#define MARG 16
#define WOUT 2048
#define HOUT 2048
#define RAD  16            // truncation radius; tail mass ~2e-7 (threshold 9.9e-3)
#define TDIM 33            // 33x33 canvas tiles of 64x64
#define NT   (TDIM * TDIM) // 1089 buckets
#define CAP  1536          // bucket capacity; expected max ~1170
#define OTD  32            // 32x32 output tiles of 64x64
#define PST  97            // patch row stride (96 cols + 1 pad -> stride mod 32 = 1)
#define NBLK 256
#define SCAT_T 1024
#define SCAT_IT 4          // 256*1024*4 >= N

// exact discrete tap via Poisson summation: g[n] = sqrt(pi/200)*exp(-pi^2 n^2/200)
__device__ __forceinline__ void make_weights(float* wreg) {
#pragma unroll
    for (int t = 0; t <= RAD; ++t)
        wreg[t] = 0.12533141373155003f * __expf(-0.04934802200544679f * (float)(t * t));
}

// 33-tap conv over a 40-window: a[k] = sum_{j=k..k+32} base[j*stride] * g[|j-k-16|]
__device__ __forceinline__ void conv8(const float* __restrict__ base, int stride,
                                      const float* __restrict__ wreg, float* __restrict__ a) {
#pragma unroll
    for (int k = 0; k < 8; ++k) a[k] = 0.0f;
#pragma unroll
    for (int j = 0; j < 40; ++j) {
        float v = base[j * stride];
#pragma unroll
        for (int k = 0; k < 8; ++k)
            if (j >= k && j <= k + 32)
                a[k] += v * wreg[(j - k - 16 < 0) ? (k + 16 - j) : (j - k - 16)];
    }
}

// ---------------------------------------------------------------------------
// pass 1: scatter into canvas-tile buckets (1.03x dup: points with cell
// row%64==63 / col%64==63 duplicated into the tile below / right, so each
// record's 2x2 footprint is tile-local, lr1/lc1 in [0,64]).
// ---------------------------------------------------------------------------
__global__ __launch_bounds__(SCAT_T) void scatter_kernel(const float2* __restrict__ pos,
                                                         const float* __restrict__ inten,
                                                         int* __restrict__ cursor,  // [NT], zeroed
                                                         ushort4* __restrict__ bins,
                                                         int n) {
    __shared__ int lhist[NT];
    __shared__ int lbase[NT];
    const int tid = threadIdx.x;
    for (int i = tid; i < NT; i += SCAT_T) lhist[i] = 0;
    __syncthreads();
    const int stride = NBLK * SCAT_T;
    const int start  = blockIdx.x * SCAT_T + tid;
    unsigned ra[SCAT_IT], rb[SCAT_IT], rc[SCAT_IT];
#pragma unroll
    for (int it = 0; it < SCAT_IT; ++it) {
        int i = start + it * stride;
        if (i < n) {
            float2 p = pos[i];
            float I  = inten[i];
            float px = p.x + MARG, py = p.y + MARG;
            int col = (int)floorf(px), row = (int)floorf(py);
            row = min(max(row, 0), HP - 1);
            col = min(max(col, 0), WP - 1);
            float dy = py - (float)row, dx = px - (float)col;
            ra[it] = ((unsigned)row << 12) | (unsigned)col;
            rb[it] = (unsigned)__half_as_ushort(__float2half(dx))
                   | ((unsigned)__half_as_ushort(__float2half(dy)) << 16);
            rc[it] = (unsigned)__half_as_ushort(__float2half(I));
            int tr = row >> 6, tc = col >> 6;
            int er = ((row & 63) == 63) ? 1 : 0;
            int ec = ((col & 63) == 63) ? 1 : 0;
            for (int dr = 0; dr <= er; ++dr)
                for (int dc = 0; dc <= ec; ++dc)
                    atomicAdd(&lhist[(tr + dr) * TDIM + tc + dc], 1);
        } else ra[it] = 0xffffffffu;
    }
    __syncthreads();
    for (int i = tid; i < NT; i += SCAT_T) {
        int c = lhist[i];
        lbase[i] = (c > 0) ? atomicAdd(&cursor[i], c) : 0;
        lhist[i] = 0;
    }
    __syncthreads();
#pragma unroll
    for (int it = 0; it < SCAT_IT; ++it) {
        if (ra[it] != 0xffffffffu) {
            int row = (int)(ra[it] >> 12), col = (int)(ra[it] & 4095u);
            int tr = row >> 6, tc = col >> 6;
            int er = ((row & 63) == 63) ? 1 : 0;
            int ec = ((col & 63) == 63) ? 1 : 0;
            for (int dr = 0; dr <= er; ++dr)
                for (int dc = 0; dc <= ec; ++dc) {
                    int b   = (tr + dr) * TDIM + tc + dc;
                    int lr1 = row - ((tr + dr) << 6) + 1;   // 0..64
                    int lc1 = col - ((tc + dc) << 6) + 1;   // 0..64
                    int off = atomicAdd(&lhist[b], 1);
                    int idx = lbase[b] + off;
                    if (idx < CAP) {
                        ushort4 rec;
                        rec.x = (unsigned short)((lr1 << 7) | lc1);
                        rec.y = (unsigned short)(rb[it] & 0xffffu);
                        rec.z = (unsigned short)(rb[it] >> 16);
                        rec.w = (unsigned short)rc[it];
                        bins[(size_t)b * CAP + idx] = rec;
                    }
                }
        }
    }
}

// ---------------------------------------------------------------------------
// pass 2 (fused): per 64x64 output tile. Gather records from the 4 buckets
// {ty,ty+1}x{tx,tx+1} (dedup: dr=1/dc=1 bucket's lr1=0/lc1=0 records are halo
// duplicates -> skip; accept lr1,lc1 <= 32). Splat into 96x96 LDS patch,
// hconv written BACK into patch cols 0..63, vconv + coalesced store.
// __launch_bounds__(512,4): VGPR cap 128. R12's (512,8) capped VGPR at 32 ->
// ~100 MB of scratch spill traffic (WRITE_SIZE 114 MB). Do NOT raise it.
// ---------------------------------------------------------------------------
__global__ __launch_bounds__(512, 4) void fused_kernel(const ushort4* __restrict__ bins,
                                                       const int* __restrict__ cursor,
                                                       float* __restrict__ out) {
    __shared__ float patch[96 * PST];   // 37.2 KB
    const int tid = threadIdx.x;
    const int tx  = blockIdx.x, ty = blockIdx.y;
    float wreg[RAD + 1];
    make_weights(wreg);

    for (int i = tid; i < 96 * PST; i += 512) patch[i] = 0.0f;
    __syncthreads();

    // --- splat from 4 buckets (patch row p = canvasrow - 64*ty) ---
    for (int q = 0; q < 4; ++q) {
        const int dr = q >> 1, dc = q & 1;
        const int bkt = (ty + dr) * TDIM + (tx + dc);
        const int cnt = min(cursor[bkt], CAP);
        const ushort4* bp = bins + (size_t)bkt * CAP;
        for (int i = tid; i < cnt; i += 512) {
            ushort4 r = bp[i];
            int lr1 = r.x >> 7, lc1 = r.x & 127;      // 0..64
            if ((dr && (lr1 < 1 || lr1 > 32)) || (dc && (lc1 < 1 || lc1 > 32))) continue;
            float dx = __half2float(__ushort_as_half(r.y));
            float dy = __half2float(__ushort_as_half(r.z));
            float I  = __half2float(__ushort_as_half(r.w));
            int p0 = (dr << 6) + lr1 - 1;             // in [-1,95]
            int c0 = (dc << 6) + lc1 - 1;             // in [-1,95]
            float wy0 = (1.0f - dy) * I, wy1 = dy * I;
            float wx0 = 1.0f - dx,      wx1 = dx;
            bool ca = (c0 >= 0), cb = (c0 <= 94);
            if (p0 >= 0) {
                if (ca) atomicAdd(&patch[p0 * PST + c0],     wy0 * wx0);
                if (cb) atomicAdd(&patch[p0 * PST + c0 + 1], wy0 * wx1);
            }
            if (p0 <= 94) {
                if (ca) atomicAdd(&patch[(p0 + 1) * PST + c0],     wy1 * wx0);
                if (cb) atomicAdd(&patch[(p0 + 1) * PST + c0 + 1], wy1 * wx1);
            }
        }
    }
    __syncthreads();

    // --- hconv into registers (row r needs patch[r][cg..cg+39]), then
    // write back into patch cols 0..63 after a barrier ---
    const int trA = tid >> 3;                 // 0..63
    const int cg  = (tid & 7) << 3;           // 0,8,...,56
    float aA[8], aB[8];
    conv8(&patch[trA * PST + cg], 1, wreg, aA);
    if (tid < 256) conv8(&patch[(64 + (tid >> 3)) * PST + cg], 1, wreg, aB);
    __syncthreads();
#pragma unroll
    for (int k = 0; k < 8; ++k) patch[trA * PST + cg + k] = aA[k];
    if (tid < 256) {
#pragma unroll
        for (int k = 0; k < 8; ++k) patch[(64 + (tid >> 3)) * PST + cg + k] = aB[k];
    }
    __syncthreads();

    // --- vconv + store ---
    const int c  = tid & 63;
    const int r0 = (tid >> 6) << 3;           // 0,8,...,56
    float a[8];
    conv8(&patch[r0 * PST + c], PST, wreg, a);
    const int oy0 = ty << 6, ox0 = tx << 6;
#pragma unroll
    for (int k = 0; k < 8; ++k)
        out[(size_t)(oy0 + r0 + k) * WOUT + ox0 + c] = a[k];
}

extern "C" void kernel_launch(void* const* d_in, const int* in_sizes, int n_in,
                              void* d_out, int out_size, void* d_ws, size_t ws_size,
                              hipStream_t stream) {
    const float2* pos   = (const float2*)d_in[0];   // (N,2) as (x,y)
    const float*  inten = (const float*)d_in[1];
    int n = in_sizes[1];

    ushort4* bins   = (ushort4*)d_ws;                             // NT*CAP*8 = 13.4 MB
    int*     cursor = (int*)((char*)d_ws + (size_t)NT * CAP * 8); // NT ints

    hipMemsetAsync(cursor, 0, NT * sizeof(int), stream);          // 4.4 KB
    scatter_kernel<<<NBLK, SCAT_T, 0, stream>>>(pos, inten, cursor, bins, n);
    fused_kernel<<<dim3(OTD, OTD), 512, 0, stream>>>(bins, cursor, (float*)d_out);
}